// Round 11
// baseline (222.918 us; speedup 1.0000x reference)
//
#include <hip/hip_runtime.h>

#define NROB 32
#define SEQ 12
#define LOBS 52
#define HID 256
#define LOUT 2
#define KIN 624            // SEQ*LOBS
#define SPB 8              // samples per chunk/block
#define NSD 24             // SEQ*LOUT
#define NBLK 160           // >= max chunks (156) ; 8 xcds x 20 slots
#define SLOTS 20

// dynamic LDS arena (float offsets):
//   [0,     4992)  x0 [8][624]   (dead after input layer -> x2 [8][256] aliases)
//   [5120,  9216)  P  [2][8][256] K-partials
//   [9216, 11264)  x1 [8][256]
//   [11264,35840)  Wt: weight tile bufs (input 4x4096 fl; hidden 3x8192 fl)
//                  dead after layers -> Wo tile S (6400 fl) aliases
#define OFF_P 5120
#define OFF_X1 9216
#define OFF_WT 11264
#define ARENA_F 35840      // 143360 bytes

#define WVM(n) asm volatile("s_waitcnt vmcnt(" #n ")" ::: "memory")

__device__ __forceinline__ void fma2(float2& a, const float2 w, const float s) {
  a.x = fmaf(w.x, s, a.x);
  a.y = fmaf(w.y, s, a.y);
}

// async global->LDS DMA, 16B/lane, 1KB/wave-instr; no VGPR destination cost.
// LDS dest: wave-uniform base + lane*16 (m104); global src per-lane.
__device__ __forceinline__ void stage1k(const float* g, float* l) {
  __builtin_amdgcn_global_load_lds(
      (const __attribute__((address_space(1))) void*)g,
      (__attribute__((address_space(3))) void*)l, 16, 0, 0);
}
// stage 16KB tile: wave w covers floats [w*512, w*512+512)
__device__ __forceinline__ void stage16(const float* Wg, float* wt, int w,
                                        int lane) {
  const float* g = Wg + w * 512 + lane * 4;
  float* l = wt + w * 512;
  stage1k(g, l);
  stage1k(g + 256, l + 256);
}
// stage 32KB tile: wave w covers floats [w*1024, w*1024+1024)
__device__ __forceinline__ void stage32(const float* Wg, float* wt, int w,
                                        int lane) {
  const float* g = Wg + w * 1024 + lane * 4;
  float* l = wt + w * 1024;
  stage1k(g, l);
  stage1k(g + 256, l + 256);
  stage1k(g + 512, l + 512);
  stage1k(g + 768, l + 768);
}

extern __shared__ float arena[];

// hidden dense layer: 8 tiles x 32 rows, 3 bufs, 2 ahead, counted vmcnt.
// wave (ks,ch): rows ks*8..+7 of each tile, cols ch*128 + lane*2.
__device__ __forceinline__ void hidden_layer(const float* __restrict__ Wg,
                                             const float* __restrict__ bias,
                                             const float* Xin, float* Xout,
                                             int ks, int ch, int cb, int w,
                                             int lane, int t) {
  float* Wt = arena + OFF_WT;
  stage32(Wg, Wt, w, lane);
  stage32(Wg + 8192, Wt + 8192, w, lane);
  float2 acc[SPB];
#pragma unroll
  for (int m = 0; m < SPB; ++m) acc[m] = {0.f, 0.f};
  for (int tt = 0; tt < 8; ++tt) {
    if (tt + 2 < 8) stage32(Wg + (tt + 2) * 8192, Wt + ((tt + 2) % 3) * 8192, w, lane);
    if (tt < 6) WVM(8); else if (tt == 6) WVM(4); else WVM(0);
    __builtin_amdgcn_s_barrier();
    const int kb = tt * 32 + ks * 8;
    const float* wr = Wt + (tt % 3) * 8192 + (ks * 8) * HID + cb;
    float2 w0 = *(const float2*)(wr);
    float2 w1 = *(const float2*)(wr + HID);
    float2 w2 = *(const float2*)(wr + 2 * HID);
    float2 w3 = *(const float2*)(wr + 3 * HID);
    float2 w4 = *(const float2*)(wr + 4 * HID);
    float2 w5 = *(const float2*)(wr + 5 * HID);
    float2 w6 = *(const float2*)(wr + 6 * HID);
    float2 w7 = *(const float2*)(wr + 7 * HID);
#pragma unroll
    for (int m = 0; m < SPB; ++m) {
      const float4 xa = *(const float4*)&Xin[m * HID + kb];
      const float4 xc = *(const float4*)&Xin[m * HID + kb + 4];
      fma2(acc[m], w0, xa.x);
      fma2(acc[m], w1, xa.y);
      fma2(acc[m], w2, xa.z);
      fma2(acc[m], w3, xa.w);
      fma2(acc[m], w4, xc.x);
      fma2(acc[m], w5, xc.y);
      fma2(acc[m], w6, xc.z);
      fma2(acc[m], w7, xc.w);
    }
    asm volatile("" ::: "memory");
    __builtin_amdgcn_s_barrier();
  }
  // partial reduce: 4 K-segs -> 2 -> finalize
  float* Pw = arena + OFF_P + (ks >> 1) * 2048 + cb;
  if ((ks & 1) == 0) {
#pragma unroll
    for (int m = 0; m < SPB; ++m) *(float2*)(Pw + m * HID) = acc[m];
  }
  __syncthreads();
  if (ks & 1) {
#pragma unroll
    for (int m = 0; m < SPB; ++m) {
      float2 c = *(const float2*)(Pw + m * HID);
      c.x += acc[m].x;
      c.y += acc[m].y;
      *(float2*)(Pw + m * HID) = c;
    }
  }
  __syncthreads();
  {
    const int m = t >> 6, c4 = (t & 63) * 4;
    const float4 p0 = *(const float4*)&arena[OFF_P + m * HID + c4];
    const float4 p1 = *(const float4*)&arena[OFF_P + 2048 + m * HID + c4];
    const float4 bv = *(const float4*)(bias + c4);
    float4 o = {fmaxf(p0.x + p1.x + bv.x, 0.f), fmaxf(p0.y + p1.y + bv.y, 0.f),
                fmaxf(p0.z + p1.z + bv.z, 0.f), fmaxf(p0.w + p1.w + bv.w, 0.f)};
    *(float4*)&Xout[m * HID + c4] = o;
  }
  __syncthreads();
}

__global__ __launch_bounds__(512, 1) void k_fused(
    const float* __restrict__ obs, const int* __restrict__ mask,
    const int* __restrict__ ids, const float* __restrict__ Wi,
    const float* __restrict__ bi, const float* __restrict__ W1,
    const float* __restrict__ b1, const float* __restrict__ W2,
    const float* __restrict__ b2, const float* __restrict__ W3,
    const float* __restrict__ b3, const float* __restrict__ Wo,
    const float* __restrict__ bo, float* __restrict__ out) {
  __shared__ int s_cnt[NROB];
  __shared__ int s_wc[8];
  __shared__ int s_h0;
  __shared__ int s_bm[SPB], s_vm[SPB], s_mb[SPB];
  __shared__ float s_ind[SPB][SEQ];

  const int t = threadIdx.x;
  const int bx = blockIdx.x;

  // ---- phase 0a: histogram ----
  if (t < NROB) s_cnt[t] = 0;
  if (t < SPB) s_bm[t] = 0;
  __syncthreads();
  const int id0 = ids[t];
  const int id1 = ids[t + 512];
  atomicAdd(&s_cnt[id0], 1);
  atomicAdd(&s_cnt[id1], 1);
  __syncthreads();

  // ---- phase 0b: deterministic chunk->block mapping (XCD-swizzled) ----
  int myr = -1, mybase = 0;
  {
    int maxbucket = 0;
    for (int x = 0; x < 8; ++x) {
      int bsum = 0;
      for (int r = x; r < NROB; r += 8) bsum += (s_cnt[r] + SPB - 1) >> 3;
      maxbucket = max(maxbucket, bsum);
    }
    if (maxbucket <= SLOTS) {
      const int myxcd = bx & 7, myslot = bx >> 3;
      int slot = 0;
      for (int r = myxcd; r < NROB; r += 8) {
        const int nch = (s_cnt[r] + SPB - 1) >> 3;
        if (myr < 0 && myslot >= slot && myslot < slot + nch) {
          myr = r;
          mybase = (myslot - slot) * SPB;
        }
        slot += nch;
      }
    } else {
      int ch = 0;
      for (int r = 0; r < NROB; ++r) {
        const int nch = (s_cnt[r] + SPB - 1) >> 3;
        if (myr < 0 && bx >= ch && bx < ch + nch) {
          myr = r;
          mybase = (bx - ch) * SPB;
        }
        ch += nch;
      }
    }
  }
  if (myr < 0) return;  // uniform across block
  const int mycnt = s_cnt[myr];

  // ---- phase 0c: stable sample ranks via ballot scan (two halves) ----
  {
    const int wv = t >> 6;
    const unsigned lane = t & 63;
    const unsigned long long m0 = __ballot(id0 == myr);
    const unsigned long long m1 = __ballot(id1 == myr);
    if (lane == 0) s_wc[wv] = __popcll(m0);
    __syncthreads();
    const unsigned long long below = (1ull << lane) - 1ull;
    int pre0 = 0;
    for (int i = 0; i < wv; ++i) pre0 += s_wc[i];
    if (id0 == myr) {
      const int j = pre0 + __popcll(m0 & below) - mybase;
      if (j >= 0 && j < SPB) s_bm[j] = t;
    }
    __syncthreads();
    if (lane == 0) s_wc[wv] = __popcll(m1);
    if (t == 0) s_h0 = 0;
    __syncthreads();
    int pre1 = 0;
    for (int i = 0; i < wv; ++i) pre1 += s_wc[i];
    if (lane == 0) atomicAdd(&s_h0, __popcll(m0));
    __syncthreads();
    if (id1 == myr) {
      const int j = s_h0 + pre1 + __popcll(m1 & below) - mybase;
      if (j >= 0 && j < SPB) s_bm[j] = t + 512;
    }
    __syncthreads();
  }
  if (t < SPB) {
    const int v = (mybase + t) < mycnt;
    s_vm[t] = v;
    int mb = 0xFFF;  // invalid slot: all-masked -> zero row
    if (v) {
      mb = 0;
      const int b = s_bm[t];
      for (int s = 0; s < SEQ; ++s) mb |= (mask[b * SEQ + s] != 0) << s;
    }
    s_mb[t] = mb;
  }
  __syncthreads();
  if (t < SPB * SEQ) {
    const int m = t / SEQ, s = t - m * SEQ;
    s_ind[m][s] = ((s_mb[m] >> s) & 1) ? 0.f : 1.f;
  }
  // ---- stage masked X0 (156 float4 per sample) ----
  for (int q = t; q < SPB * (KIN / 4); q += 512) {
    const int m = q / 156, f4 = q - m * 156;
    const int s = f4 / 13;
    float4 v = {0.f, 0.f, 0.f, 0.f};
    if (!((s_mb[m] >> s) & 1))
      v = *(const float4*)(obs + (size_t)s_bm[m] * KIN + f4 * 4);
    *(float4*)&arena[m * KIN + f4 * 4] = v;
  }
  __syncthreads();

  // wave decomposition: 8 waves = 4 K-segs x 2 col-halves; lane owns 2 cols
  const int w = t >> 6, lane = t & 63;
  const int ks = w >> 1, ch = w & 1;
  const int cb = ch * 128 + lane * 2;
  float* x1 = arena + OFF_X1;
  float* x2 = arena;  // aliases dead x0

  // ---- input layer: 39 tiles x 16 rows, 4 bufs, 3 ahead ----
  {
    const float* Wg = Wi + (size_t)myr * KIN * HID;
    float* Wt = arena + OFF_WT;
    stage16(Wg, Wt, w, lane);
    stage16(Wg + 4096, Wt + 4096, w, lane);
    stage16(Wg + 8192, Wt + 8192, w, lane);
    float2 acc[SPB];
#pragma unroll
    for (int m = 0; m < SPB; ++m) acc[m] = {0.f, 0.f};
    for (int tt = 0; tt < 39; ++tt) {
      if (tt + 3 < 39)
        stage16(Wg + (size_t)(tt + 3) * 4096, Wt + ((tt + 3) & 3) * 4096, w, lane);
      if (tt < 36) WVM(6); else if (tt == 36) WVM(4); else if (tt == 37) WVM(2); else WVM(0);
      __builtin_amdgcn_s_barrier();
      const int kb = tt * 16 + ks * 4;
      const float* wr = Wt + (tt & 3) * 4096 + (ks * 4) * HID + cb;
      float2 w0 = *(const float2*)(wr);
      float2 w1 = *(const float2*)(wr + HID);
      float2 w2 = *(const float2*)(wr + 2 * HID);
      float2 w3 = *(const float2*)(wr + 3 * HID);
#pragma unroll
      for (int m = 0; m < SPB; ++m) {
        const float4 xv = *(const float4*)&arena[m * KIN + kb];
        fma2(acc[m], w0, xv.x);
        fma2(acc[m], w1, xv.y);
        fma2(acc[m], w2, xv.z);
        fma2(acc[m], w3, xv.w);
      }
      asm volatile("" ::: "memory");
      __builtin_amdgcn_s_barrier();
    }
    float* Pw = arena + OFF_P + (ks >> 1) * 2048 + cb;
    if ((ks & 1) == 0) {
#pragma unroll
      for (int m = 0; m < SPB; ++m) *(float2*)(Pw + m * HID) = acc[m];
    }
    __syncthreads();
    if (ks & 1) {
#pragma unroll
      for (int m = 0; m < SPB; ++m) {
        float2 c = *(const float2*)(Pw + m * HID);
        c.x += acc[m].x;
        c.y += acc[m].y;
        *(float2*)(Pw + m * HID) = c;
      }
    }
    __syncthreads();
    {  // finalize: + sum_s ind*bi_s, relu -> x1
      const int m = t >> 6, c4 = (t & 63) * 4;
      const float4 p0 = *(const float4*)&arena[OFF_P + m * HID + c4];
      const float4 p1 = *(const float4*)&arena[OFF_P + 2048 + m * HID + c4];
      float4 a = {p0.x + p1.x, p0.y + p1.y, p0.z + p1.z, p0.w + p1.w};
      const float* br = bi + (size_t)myr * SEQ * HID + c4;
#pragma unroll
      for (int s = 0; s < SEQ; ++s) {
        const float4 b4 = *(const float4*)(br + s * HID);
        const float f = s_ind[m][s];
        a.x = fmaf(b4.x, f, a.x);
        a.y = fmaf(b4.y, f, a.y);
        a.z = fmaf(b4.z, f, a.z);
        a.w = fmaf(b4.w, f, a.w);
      }
      float4 o = {fmaxf(a.x, 0.f), fmaxf(a.y, 0.f), fmaxf(a.z, 0.f),
                  fmaxf(a.w, 0.f)};
      *(float4*)&x1[m * HID + c4] = o;
    }
    __syncthreads();
  }

  // ---- hidden layers ----
  hidden_layer(W1 + (size_t)myr * HID * HID, b1 + (size_t)myr * HID, x1, x2,
               ks, ch, cb, w, lane, t);
  hidden_layer(W2 + (size_t)myr * HID * HID, b2 + (size_t)myr * HID, x2, x1,
               ks, ch, cb, w, lane, t);
  hidden_layer(W3 + (size_t)myr * HID * HID, b3 + (size_t)myr * HID, x1, x2,
               ks, ch, cb, w, lane, t);
  // final activations in x2

  // ---- output hypernetwork: Wo tile S[k*25 + sd] (conflict-free), at Wt ----
  float* S = arena + OFF_WT;  // 6400 fl, Wt dead (all DMA drained: WVM(0) at tail)
  {
    const float* Wop = Wo + (size_t)myr * SEQ * HID * LOUT;
    for (int q = t; q < (NSD * HID) / 4; q += 512) {
      const float4 v = *(const float4*)(Wop + q * 4);
      const int flat = q * 4;
      const int s = flat >> 9;          // / (HID*LOUT)
      const int k = (flat & 511) >> 1;  // d-pairs packed in float4
      S[(k + 0) * 25 + s * 2 + 0] = v.x;
      S[(k + 0) * 25 + s * 2 + 1] = v.y;
      S[(k + 1) * 25 + s * 2 + 0] = v.z;
      S[(k + 1) * 25 + s * 2 + 1] = v.w;
    }
  }
  __syncthreads();
  if (t < SPB * NSD) {  // 192 threads: one (sample, s*2+d) each
    const int m = t / NSD, sd = t - m * NSD;
    float a = bo[(size_t)myr * NSD + sd];
    const float* xp = x2 + m * HID;
#pragma unroll 8
    for (int k = 0; k < HID; ++k) a = fmaf(xp[k], S[k * 25 + sd], a);
    if (s_vm[m]) out[(size_t)s_bm[m] * NSD + sd] = a;
  }
}

extern "C" void kernel_launch(void* const* d_in, const int* in_sizes, int n_in,
                              void* d_out, int out_size, void* d_ws, size_t ws_size,
                              hipStream_t stream) {
  const float* obs = (const float*)d_in[0];
  const int* mask = (const int*)d_in[1];
  const int* ids = (const int*)d_in[2];
  const float* Wi = (const float*)d_in[3];
  const float* bi = (const float*)d_in[4];
  const float* W1 = (const float*)d_in[5];
  const float* b1 = (const float*)d_in[6];
  const float* W2 = (const float*)d_in[7];
  const float* b2 = (const float*)d_in[8];
  const float* W3 = (const float*)d_in[9];
  const float* b3 = (const float*)d_in[10];
  const float* Wo = (const float*)d_in[11];
  const float* bo = (const float*)d_in[12];
  float* out = (float*)d_out;
  (void)d_ws;

  (void)hipFuncSetAttribute((const void*)k_fused,
                            hipFuncAttributeMaxDynamicSharedMemorySize,
                            ARENA_F * 4);
  hipLaunchKernelGGL(k_fused, dim3(NBLK), dim3(512), ARENA_F * 4, stream, obs,
                     mask, ids, Wi, bi, W1, b1, W2, b2, W3, b3, Wo, bo, out);
}

// Round 12
// 155.593 us; speedup vs baseline: 1.4327x; 1.4327x over previous
//
#include <hip/hip_runtime.h>

#define NROB 32
#define SEQ 12
#define LOBS 52
#define HID 256
#define LOUT 2
#define BATCH 1024
#define KIN 624
#define GSZ 32             // samples per compute group
#define NB 256             // 32 robots x 8 col-groups; 1 block/CU -> all resident
#define NSD 24

// ws layout: ctr[8] ints at 0; ebufA floats at 64; ebufB at 64+256K
#define WS_EA 64
#define WS_EB (64 + BATCH * HID)

// dynamic LDS arena (floats):
//   [0,     22464)  Wl  [624][36] input-weight slice (hidden reuses [256][36])
//   [22464, 30784)  xl  [32][260] act tile (input obs chunk [32][108] aliases)
//   [30784, 31168)  bil [12][32] input bias slice
//   [31168, 31936)  S   [3][256] output-weight slice
//   [31936, 31968)  bhl [32] hidden bias slice
#define OFF_XL 22464
#define OFF_BIL 30784
#define OFF_S 31168
#define OFF_BHL 31936
#define ARENA2 31968       // 127872 bytes

__device__ __forceinline__ void fma2(float2& a, const float2 w, const float s) {
  a.x = fmaf(w.x, s, a.x);
  a.y = fmaf(w.y, s, a.y);
}

extern __shared__ float arena[];

__global__ void k_init(int* ctr) {
  if (threadIdx.x < 8) ctr[threadIdx.x] = 0;
}

// grid barrier: all 256 blocks resident (125KB LDS -> 1 block/CU, 256 CUs).
// release flushes writer L2; acquire invalidates reader caches (cross-XCD).
__device__ __forceinline__ void gsync(int* ctr, int phase, int t) {
  __syncthreads();  // drains vmcnt(0): all this block's stores in L2
  if (t == 0) {
    __hip_atomic_fetch_add(&ctr[phase], 1, __ATOMIC_RELEASE,
                           __HIP_MEMORY_SCOPE_AGENT);
    while (__hip_atomic_load(&ctr[phase], __ATOMIC_ACQUIRE,
                             __HIP_MEMORY_SCOPE_AGENT) < NB) {
    }
  }
  __syncthreads();
}

__global__ __launch_bounds__(512, 1) void k_coop(
    const float* __restrict__ obs, const int* __restrict__ mask,
    const int* __restrict__ ids, const float* __restrict__ Wi,
    const float* __restrict__ bi, const float* __restrict__ W1,
    const float* __restrict__ b1, const float* __restrict__ W2,
    const float* __restrict__ b2, const float* __restrict__ W3,
    const float* __restrict__ b3, const float* __restrict__ Wo,
    const float* __restrict__ bo, float* __restrict__ out, int* ctr,
    float* ebA, float* ebB) {
  __shared__ int list[BATCH];
  __shared__ int s_cnt;
  __shared__ int mbg[GSZ], bga[GSZ];
  __shared__ float s_bo3[3];
  float* Wl = arena;
  float* xl = arena + OFF_XL;
  float* bil = arena + OFF_BIL;
  float* S = arena + OFF_S;
  float* bhl = arena + OFF_BHL;

  const int t = threadIdx.x;
  const int bx = blockIdx.x;
  // block -> (robot, col-group), XCD-aligned: all 8 cg-blocks of robot r on
  // XCD r&7 (dispatch round-robin bx%8). bijective over 256.
  const int xcd = bx & 7, slot = bx >> 3;
  const int r = ((slot >> 3) << 3) | xcd;  // 0..31
  const int cg = slot & 7;                 // 0..7 -> cols [cg*32, cg*32+32)

  // ---- sample list for robot r: wave 0, in-order ballot scan ----
  if (t < 64) {
    int running = 0;
    for (int c = 0; c < 16; ++c) {
      const int b = c * 64 + t;
      const int id = ids[b];
      const unsigned long long mb = __ballot(id == r);
      if (id == r) {
        const int rank = running + __popcll(mb & ((1ull << t) - 1ull));
        list[rank] = b;
      }
      running += __popcll(mb);
    }
    if (t == 0) s_cnt = running;
  }
  // ---- stage input weight slice Wi[r][:, cg*32:+32] -> Wl[624][36] ----
  {
    const float* Wg = Wi + ((size_t)r * KIN) * HID + cg * 32;
    for (int q = t; q < KIN * 8; q += 512) {
      const int k = q >> 3, c4 = q & 7;
      const float4 v = *(const float4*)(Wg + (size_t)k * HID + c4 * 4);
      *(float4*)&Wl[k * 36 + c4 * 4] = v;
    }
    if (t < SEQ * 32)
      bil[t] = bi[(size_t)r * SEQ * HID + (t >> 5) * HID + cg * 32 + (t & 31)];
  }
  __syncthreads();
  const int cnt = s_cnt;
  const int ng = (cnt + GSZ - 1) / GSZ;
  const int m = t >> 4, c2 = t & 15;  // compute coords: 32 samples x 16 col-pairs

  // ---- input layer: e0 = relu(sum_s masked obs . Wi + ind.bi) -> ebA ----
  for (int g = 0; g < ng; ++g) {
    if (t < GSZ) {
      const int mm = g * GSZ + t;
      const int valid = mm < cnt;
      const int b = list[valid ? mm : 0];
      int mb = 0xFFF;
      if (valid) {
        mb = 0;
        for (int s = 0; s < SEQ; ++s) mb |= (mask[b * SEQ + s] != 0) << s;
      }
      mbg[t] = mb;
      bga[t] = b;
    }
    __syncthreads();
    float2 acc = {0.f, 0.f};
    for (int ch = 0; ch < 6; ++ch) {  // 6 chunks x 104 k
      for (int q2 = t; q2 < GSZ * 26; q2 += 512) {
        const int mm = q2 / 26, q = q2 - mm * 26;
        const int s = ch * 2 + (q >= 13);
        float4 v = {0.f, 0.f, 0.f, 0.f};
        if (!((mbg[mm] >> s) & 1))
          v = *(const float4*)(obs + (size_t)bga[mm] * KIN + ch * 104 + q * 4);
        *(float4*)&xl[mm * 108 + q * 4] = v;
      }
      __syncthreads();
      for (int q = 0; q < 26; ++q) {
        const float4 x4 = *(const float4*)&xl[m * 108 + q * 4];
        const int k = ch * 104 + q * 4;
        const float2 w0 = *(const float2*)&Wl[(k + 0) * 36 + c2 * 2];
        const float2 w1 = *(const float2*)&Wl[(k + 1) * 36 + c2 * 2];
        const float2 w2 = *(const float2*)&Wl[(k + 2) * 36 + c2 * 2];
        const float2 w3 = *(const float2*)&Wl[(k + 3) * 36 + c2 * 2];
        fma2(acc, w0, x4.x);
        fma2(acc, w1, x4.y);
        fma2(acc, w2, x4.z);
        fma2(acc, w3, x4.w);
      }
      __syncthreads();
    }
    const int mb = mbg[m];
#pragma unroll
    for (int s = 0; s < SEQ; ++s) {
      const float f = ((mb >> s) & 1) ? 0.f : 1.f;
      fma2(acc, *(const float2*)&bil[s * 32 + c2 * 2], f);
    }
    if (g * GSZ + m < cnt) {
      float2 o = {fmaxf(acc.x, 0.f), fmaxf(acc.y, 0.f)};
      *(float2*)&ebA[(size_t)bga[m] * HID + cg * 32 + c2 * 2] = o;
    }
    __syncthreads();
  }
  gsync(ctr, 0, t);

  // ---- hidden layers: A->B, B->A, A->B ----
  const float* Ws[3] = {W1, W2, W3};
  const float* bs[3] = {b1, b2, b3};
  for (int L = 0; L < 3; ++L) {
    const float* src = (L & 1) ? ebB : ebA;
    float* dst = (L & 1) ? ebA : ebB;
    {  // stage W slice [256][36] + bias slice
      const float* Wg = Ws[L] + ((size_t)r * HID) * HID + cg * 32;
      for (int q = t; q < HID * 8; q += 512) {
        const int k = q >> 3, c4 = q & 7;
        const float4 v = *(const float4*)(Wg + (size_t)k * HID + c4 * 4);
        *(float4*)&Wl[k * 36 + c4 * 4] = v;
      }
      if (t < 32) bhl[t] = bs[L][(size_t)r * HID + cg * 32 + t];
    }
    __syncthreads();
    for (int g = 0; g < ng; ++g) {
      if (t < GSZ) {
        const int mm = g * GSZ + t;
        bga[t] = list[(mm < cnt) ? mm : 0];
      }
      __syncthreads();
      for (int q2 = t; q2 < GSZ * 64; q2 += 512) {
        const int mm = q2 >> 6, k4 = q2 & 63;
        const float4 v = *(const float4*)(src + (size_t)bga[mm] * HID + k4 * 4);
        *(float4*)&xl[mm * 260 + k4 * 4] = v;
      }
      __syncthreads();
      float2 acc = {0.f, 0.f};
      for (int k4 = 0; k4 < 64; ++k4) {
        const float4 x4 = *(const float4*)&xl[m * 260 + k4 * 4];
        const int k = k4 * 4;
        const float2 w0 = *(const float2*)&Wl[(k + 0) * 36 + c2 * 2];
        const float2 w1 = *(const float2*)&Wl[(k + 1) * 36 + c2 * 2];
        const float2 w2 = *(const float2*)&Wl[(k + 2) * 36 + c2 * 2];
        const float2 w3 = *(const float2*)&Wl[(k + 3) * 36 + c2 * 2];
        fma2(acc, w0, x4.x);
        fma2(acc, w1, x4.y);
        fma2(acc, w2, x4.z);
        fma2(acc, w3, x4.w);
      }
      if (g * GSZ + m < cnt) {
        const float2 bv = *(const float2*)&bhl[c2 * 2];
        float2 o = {fmaxf(acc.x + bv.x, 0.f), fmaxf(acc.y + bv.y, 0.f)};
        *(float2*)&dst[(size_t)bga[m] * HID + cg * 32 + c2 * 2] = o;
      }
      __syncthreads();
    }
    gsync(ctr, L + 1, t);
  }

  // ---- output: this block covers sd in [cg*3, cg*3+3) of its samples ----
  {
    const float* Wor = Wo + (size_t)r * SEQ * HID * LOUT;
    for (int q = t; q < 3 * HID; q += 512) {
      const int j = q >> 8, k = q & 255;
      const int sd = cg * 3 + j;
      S[j * 256 + k] = Wor[(sd >> 1) * (HID * LOUT) + k * 2 + (sd & 1)];
    }
    if (t < 3) s_bo3[t] = bo[(size_t)r * NSD + cg * 3 + t];
  }
  __syncthreads();
  for (int g = 0; g < ng; ++g) {
    if (t < GSZ) {
      const int mm = g * GSZ + t;
      bga[t] = list[(mm < cnt) ? mm : 0];
    }
    __syncthreads();
    for (int q2 = t; q2 < GSZ * 64; q2 += 512) {
      const int mm = q2 >> 6, k4 = q2 & 63;
      const float4 v = *(const float4*)(ebB + (size_t)bga[mm] * HID + k4 * 4);
      *(float4*)&xl[mm * 260 + k4 * 4] = v;
    }
    __syncthreads();
    if (t < GSZ * 3) {
      const int mo = t / 3, j = t - mo * 3;
      float a = s_bo3[j];
      for (int k4 = 0; k4 < 64; ++k4) {
        const float4 x4 = *(const float4*)&xl[mo * 260 + k4 * 4];
        const float4 s4 = *(const float4*)&S[j * 256 + k4 * 4];
        a = fmaf(x4.x, s4.x, a);
        a = fmaf(x4.y, s4.y, a);
        a = fmaf(x4.z, s4.z, a);
        a = fmaf(x4.w, s4.w, a);
      }
      if (g * GSZ + mo < cnt) out[(size_t)bga[mo] * NSD + cg * 3 + j] = a;
    }
    __syncthreads();
  }
}

extern "C" void kernel_launch(void* const* d_in, const int* in_sizes, int n_in,
                              void* d_out, int out_size, void* d_ws, size_t ws_size,
                              hipStream_t stream) {
  const float* obs = (const float*)d_in[0];
  const int* mask = (const int*)d_in[1];
  const int* ids = (const int*)d_in[2];
  const float* Wi = (const float*)d_in[3];
  const float* bi = (const float*)d_in[4];
  const float* W1 = (const float*)d_in[5];
  const float* b1 = (const float*)d_in[6];
  const float* W2 = (const float*)d_in[7];
  const float* b2 = (const float*)d_in[8];
  const float* W3 = (const float*)d_in[9];
  const float* b3 = (const float*)d_in[10];
  const float* Wo = (const float*)d_in[11];
  const float* bo = (const float*)d_in[12];
  float* out = (float*)d_out;
  int* ctr = (int*)d_ws;
  float* ebA = (float*)d_ws + WS_EA;
  float* ebB = (float*)d_ws + WS_EB;

  (void)hipFuncSetAttribute((const void*)k_coop,
                            hipFuncAttributeMaxDynamicSharedMemorySize,
                            ARENA2 * 4);
  hipLaunchKernelGGL(k_init, dim3(1), dim3(64), 0, stream, ctr);
  hipLaunchKernelGGL(k_coop, dim3(NB), dim3(512), ARENA2 * 4, stream, obs,
                     mask, ids, Wi, bi, W1, b1, W2, b2, W3, b3, Wo, bo, out,
                     ctr, ebA, ebB);
}

// Round 13
// 51.615 us; speedup vs baseline: 4.3189x; 3.0145x over previous
//
#include <hip/hip_runtime.h>

#define NROB 32
#define SEQ 12
#define LOBS 52
#define HID 256
#define LOUT 2
#define BATCH 1024
#define KIN 624            // SEQ*LOBS
#define SPB 8              // samples per chunk/block
#define NSD 24             // SEQ*LOUT
#define NBLK 160           // >= max chunks (156); 8 xcds x 20 slots
#define SLOTS 20

// static LDS arena (float offsets), 15232 fl = 60928 B:
//   [0,     4992)  x0 [8][624]   (dead after input layer -> x2 [8][256] aliases)
//   [4992, 13184)  P  [4][8][256] K-partials (dead after L3 -> Wo tile S aliases)
//   [13184,15232)  x1 [8][256]
#define OFF_P 4992
#define OFF_X1 13184
#define ARENA_F 15232

__device__ __forceinline__ void fma4(float4& a, const float4 w, const float s) {
  a.x = fmaf(w.x, s, a.x);
  a.y = fmaf(w.y, s, a.y);
  a.z = fmaf(w.z, s, a.z);
  a.w = fmaf(w.w, s, a.w);
}

// Stream ROWS weight rows (stride HID floats, float4/lane = 1KB/wave) against
// 8 samples (LDS broadcast b128 covers 4 k's). A/B 4-row register buffers:
// acc 32 + A/B 32 VGPR fits the 128-VGPR cap of a 1024-thread block.
template <int ROWS, int XS>
__device__ __forceinline__ void stream8(const float* __restrict__ wp,
                                        const float* xb, float4* acc) {
  static_assert(ROWS % 8 == 0, "ROWS multiple of 8");
  constexpr int G = ROWS / 4;  // even
  float4 A[4], B[4];
#pragma unroll
  for (int j = 0; j < 4; ++j) A[j] = *(const float4*)(wp + j * HID);
#pragma unroll
  for (int j = 0; j < 4; ++j) B[j] = *(const float4*)(wp + (4 + j) * HID);
#pragma unroll
  for (int g = 0; g < G; g += 2) {
    const int k = g * 4;
#pragma unroll
    for (int m = 0; m < SPB; ++m) {
      const float4 x = *(const float4*)(xb + m * XS + k);
      fma4(acc[m], A[0], x.x);
      fma4(acc[m], A[1], x.y);
      fma4(acc[m], A[2], x.z);
      fma4(acc[m], A[3], x.w);
    }
    if (g + 2 < G) {
#pragma unroll
      for (int j = 0; j < 4; ++j)
        A[j] = *(const float4*)(wp + (size_t)(k + 8 + j) * HID);
    }
#pragma unroll
    for (int m = 0; m < SPB; ++m) {
      const float4 x = *(const float4*)(xb + m * XS + k + 4);
      fma4(acc[m], B[0], x.x);
      fma4(acc[m], B[1], x.y);
      fma4(acc[m], B[2], x.z);
      fma4(acc[m], B[3], x.w);
    }
    if (g + 3 < G) {
#pragma unroll
      for (int j = 0; j < 4; ++j)
        B[j] = *(const float4*)(wp + (size_t)(k + 12 + j) * HID);
    }
  }
}

__global__ __launch_bounds__(1024, 4) void k_fused(
    const float* __restrict__ obs, const int* __restrict__ mask,
    const int* __restrict__ ids, const float* __restrict__ Wi,
    const float* __restrict__ bi, const float* __restrict__ W1,
    const float* __restrict__ b1, const float* __restrict__ W2,
    const float* __restrict__ b2, const float* __restrict__ W3,
    const float* __restrict__ b3, const float* __restrict__ Wo,
    const float* __restrict__ bo, float* __restrict__ out) {
  __shared__ int s_cnt[NROB];
  __shared__ int s_wc[16];
  __shared__ int s_bm[SPB], s_vm[SPB], s_mb[SPB];
  __shared__ float s_ind[SPB][SEQ];
  __shared__ __align__(16) float sm[ARENA_F];  // 60928 B static -> compiler sees it
  float* x0 = sm;
  float* P = sm + OFF_P;
  float* x1 = sm + OFF_X1;
  float* x2 = sm;  // aliases dead x0

  const int t = threadIdx.x;
  const int bx = blockIdx.x;

  // ---- phase 0a: histogram (1024 threads = all samples, one pass) ----
  if (t < NROB) s_cnt[t] = 0;
  if (t < SPB) s_bm[t] = 0;
  __syncthreads();
  const int id0 = ids[t];
  atomicAdd(&s_cnt[id0], 1);
  __syncthreads();

  // ---- phase 0b: deterministic chunk->block mapping (XCD-swizzled) ----
  int myr = -1, mybase = 0;
  {
    int maxbucket = 0;
    for (int x = 0; x < 8; ++x) {
      int bsum = 0;
      for (int r = x; r < NROB; r += 8) bsum += (s_cnt[r] + SPB - 1) >> 3;
      maxbucket = max(maxbucket, bsum);
    }
    if (maxbucket <= SLOTS) {
      const int myxcd = bx & 7, myslot = bx >> 3;
      int slot = 0;
      for (int r = myxcd; r < NROB; r += 8) {
        const int nch = (s_cnt[r] + SPB - 1) >> 3;
        if (myr < 0 && myslot >= slot && myslot < slot + nch) {
          myr = r;
          mybase = (myslot - slot) * SPB;
        }
        slot += nch;
      }
    } else {
      int ch = 0;
      for (int r = 0; r < NROB; ++r) {
        const int nch = (s_cnt[r] + SPB - 1) >> 3;
        if (myr < 0 && bx >= ch && bx < ch + nch) {
          myr = r;
          mybase = (bx - ch) * SPB;
        }
        ch += nch;
      }
    }
  }
  if (myr < 0) return;  // uniform across block
  const int mycnt = s_cnt[myr];

  // ---- phase 0c: stable sample ranks via ballot scan (one pass) ----
  {
    const int wv = t >> 6;
    const unsigned lane = t & 63;
    const unsigned long long m0 = __ballot(id0 == myr);
    if (lane == 0) s_wc[wv] = __popcll(m0);
    __syncthreads();
    int pre = 0;
    for (int i = 0; i < wv; ++i) pre += s_wc[i];
    if (id0 == myr) {
      const unsigned long long below = (1ull << lane) - 1ull;
      const int j = pre + __popcll(m0 & below) - mybase;
      if (j >= 0 && j < SPB) s_bm[j] = t;
    }
    __syncthreads();
  }
  if (t < SPB) {
    const int v = (mybase + t) < mycnt;
    s_vm[t] = v;
    int mb = 0xFFF;  // invalid slot: all-masked -> zero row
    if (v) {
      mb = 0;
      const int b = s_bm[t];
      for (int s = 0; s < SEQ; ++s) mb |= (mask[b * SEQ + s] != 0) << s;
    }
    s_mb[t] = mb;
  }
  __syncthreads();
  if (t < SPB * SEQ) {
    const int m = t / SEQ, s = t - m * SEQ;
    s_ind[m][s] = ((s_mb[m] >> s) & 1) ? 0.f : 1.f;
  }
  // ---- stage masked X0 (156 float4 per sample) ----
  for (int q = t; q < SPB * (KIN / 4); q += 1024) {
    const int m = q / 156, f4 = q - m * 156;
    const int s = f4 / 13;
    float4 v = {0.f, 0.f, 0.f, 0.f};
    if (!((s_mb[m] >> s) & 1))
      v = *(const float4*)(obs + (size_t)s_bm[m] * KIN + f4 * 4);
    *(float4*)&x0[m * KIN + f4 * 4] = v;
  }
  __syncthreads();

  // 16 waves = 16 K-segments; lane owns 4 cols (lane*4)
  const int w = t >> 6, lane = t & 63;
  float* Pw = P + (w & 3) * (SPB * HID) + lane * 4;

  // ---- input layer: segs 0-14 have 40 rows, seg 15 has 24 ----
  {
    float4 acc[SPB];
#pragma unroll
    for (int m = 0; m < SPB; ++m) acc[m] = {0.f, 0.f, 0.f, 0.f};
    const float* Wr = Wi + ((size_t)myr * KIN + w * 40) * HID + lane * 4;
    const float* xb = x0 + w * 40;
    if (w < 15)
      stream8<40, KIN>(Wr, xb, acc);
    else
      stream8<24, KIN>(Wr, xb, acc);
    // 4-round cross-wave reduce into P[w&3]
    if (w < 4) {
#pragma unroll
      for (int m = 0; m < SPB; ++m) *(float4*)(Pw + m * HID) = acc[m];
    }
    __syncthreads();
#pragma unroll
    for (int rnd = 1; rnd < 4; ++rnd) {
      if ((w >> 2) == rnd) {
#pragma unroll
        for (int m = 0; m < SPB; ++m) {
          float4 c = *(const float4*)(Pw + m * HID);
          c.x += acc[m].x;
          c.y += acc[m].y;
          c.z += acc[m].z;
          c.w += acc[m].w;
          *(float4*)(Pw + m * HID) = c;
        }
      }
      __syncthreads();
    }
    {  // finalize: sum 4 partials + sum_s ind*bi_s, relu -> x1 (float2/thread)
      const int m = t >> 7, c2 = (t & 127) * 2;
      float2 a = {0.f, 0.f};
#pragma unroll
      for (int j = 0; j < 4; ++j) {
        const float2 p = *(const float2*)&P[(j * SPB + m) * HID + c2];
        a.x += p.x;
        a.y += p.y;
      }
      const float* br = bi + (size_t)myr * SEQ * HID + c2;
#pragma unroll
      for (int s = 0; s < SEQ; ++s) {
        const float2 b2v = *(const float2*)(br + s * HID);
        const float f = s_ind[m][s];
        a.x = fmaf(b2v.x, f, a.x);
        a.y = fmaf(b2v.y, f, a.y);
      }
      x1[m * HID + c2] = fmaxf(a.x, 0.f);
      x1[m * HID + c2 + 1] = fmaxf(a.y, 0.f);
    }
    __syncthreads();
  }

  // ---- hidden layers: 16 rows per seg ----
  const float* Ws[3] = {W1, W2, W3};
  const float* bs[3] = {b1, b2, b3};
#pragma unroll
  for (int L = 0; L < 3; ++L) {
    const float* Xin = (L & 1) ? x2 : x1;  // L0: x1->x2, L1: x2->x1, L2: x1->x2
    float* Xout = (L & 1) ? x1 : x2;
    float4 acc[SPB];
#pragma unroll
    for (int m = 0; m < SPB; ++m) acc[m] = {0.f, 0.f, 0.f, 0.f};
    const float* Wr = Ws[L] + ((size_t)myr * HID + w * 16) * HID + lane * 4;
    stream8<16, HID>(Wr, Xin + w * 16, acc);
    if (w < 4) {
#pragma unroll
      for (int m = 0; m < SPB; ++m) *(float4*)(Pw + m * HID) = acc[m];
    }
    __syncthreads();
#pragma unroll
    for (int rnd = 1; rnd < 4; ++rnd) {
      if ((w >> 2) == rnd) {
#pragma unroll
        for (int m = 0; m < SPB; ++m) {
          float4 c = *(const float4*)(Pw + m * HID);
          c.x += acc[m].x;
          c.y += acc[m].y;
          c.z += acc[m].z;
          c.w += acc[m].w;
          *(float4*)(Pw + m * HID) = c;
        }
      }
      __syncthreads();
    }
    {
      const int m = t >> 7, c2 = (t & 127) * 2;
      float2 a = {0.f, 0.f};
#pragma unroll
      for (int j = 0; j < 4; ++j) {
        const float2 p = *(const float2*)&P[(j * SPB + m) * HID + c2];
        a.x += p.x;
        a.y += p.y;
      }
      const float2 bv = *(const float2*)(bs[L] + (size_t)myr * HID + c2);
      Xout[m * HID + c2] = fmaxf(a.x + bv.x, 0.f);
      Xout[m * HID + c2 + 1] = fmaxf(a.y + bv.y, 0.f);
    }
    __syncthreads();
  }
  // final activations in x2

  // ---- output hypernetwork: Wo tile S[k*25 + sd] (conflict-free), at P ----
  float* S = P;  // 6400 fl <= 8192, P dead
  {
    const float* Wop = Wo + (size_t)myr * SEQ * HID * LOUT;
    for (int q = t; q < (NSD * HID) / 4; q += 1024) {
      const float4 v = *(const float4*)(Wop + q * 4);
      const int flat = q * 4;
      const int s = flat >> 9;          // / (HID*LOUT)
      const int k = (flat & 511) >> 1;  // d-pairs packed in float4
      S[(k + 0) * 25 + s * 2 + 0] = v.x;
      S[(k + 0) * 25 + s * 2 + 1] = v.y;
      S[(k + 1) * 25 + s * 2 + 0] = v.z;
      S[(k + 1) * 25 + s * 2 + 1] = v.w;
    }
  }
  __syncthreads();
  if (t < SPB * NSD) {  // 192 threads: one (sample, s*2+d) each
    const int m = t / NSD, sd = t - m * NSD;
    float a = bo[(size_t)myr * NSD + sd];
    const float* xp = x2 + m * HID;
#pragma unroll 8
    for (int k = 0; k < HID; ++k) a = fmaf(xp[k], S[k * 25 + sd], a);
    if (s_vm[m]) out[(size_t)s_bm[m] * NSD + sd] = a;
  }
}

extern "C" void kernel_launch(void* const* d_in, const int* in_sizes, int n_in,
                              void* d_out, int out_size, void* d_ws, size_t ws_size,
                              hipStream_t stream) {
  const float* obs = (const float*)d_in[0];
  const int* mask = (const int*)d_in[1];
  const int* ids = (const int*)d_in[2];
  const float* Wi = (const float*)d_in[3];
  const float* bi = (const float*)d_in[4];
  const float* W1 = (const float*)d_in[5];
  const float* b1 = (const float*)d_in[6];
  const float* W2 = (const float*)d_in[7];
  const float* b2 = (const float*)d_in[8];
  const float* W3 = (const float*)d_in[9];
  const float* b3 = (const float*)d_in[10];
  const float* Wo = (const float*)d_in[11];
  const float* bo = (const float*)d_in[12];
  float* out = (float*)d_out;
  (void)d_ws;

  hipLaunchKernelGGL(k_fused, dim3(NBLK), dim3(1024), 0, stream, obs, mask,
                     ids, Wi, bi, W1, b1, W2, b2, W3, b3, Wo, bo, out);
}